// Round 1
// 2468.810 us; speedup vs baseline: 1.0475x; 1.0475x over previous
//
#include <hip/hip_runtime.h>
#include <cmath>

constexpr int NB   = 16;      // batch
constexpr int NPTS = 10000;   // points per batch
constexpr int NBN  = NB * NPTS;   // 160000
constexpr int NS_ITERS = 18;
constexpr int COV_CHUNKS = 20;    // 500 points each
constexpr int CHUNK_PTS  = 500;
constexpr int COV_KK     = 16;    // 16*32 = 512 >= 500

typedef __bf16 bf16x8 __attribute__((ext_vector_type(8)));
typedef float  f32x4  __attribute__((ext_vector_type(4)));
typedef unsigned short ushort4v __attribute__((ext_vector_type(4)));

// ---------------------------------------------------------------------------
// Layer 0: 3 -> 64, no input BN
// ---------------------------------------------------------------------------
__global__ __launch_bounds__(256) void conv0_ker(const float* __restrict__ pts,
                                                 const float* __restrict__ W,
                                                 float* __restrict__ y) {
    int g = blockIdx.x * 256 + threadIdx.x;          // 0..159999
    int b = g / NPTS;
    int n = g - b * NPTS;
    float p0 = pts[3 * (size_t)g + 0];
    float p1 = pts[3 * (size_t)g + 1];
    float p2 = pts[3 * (size_t)g + 2];
    float* yp = y + ((size_t)b * 64) * NPTS + n;
    for (int o = 0; o < 64; ++o) {
        float v = W[3 * o] * p0 + W[3 * o + 1] * p1 + W[3 * o + 2] * p2;
        yp[(size_t)o * NPTS] = v;
    }
}

// ---------------------------------------------------------------------------
// Tiled GEMM conv layer: y[b, ob+o, n] = sum_c W[ob+o, c] * relu(bn(x[b, c, n]))
// ---------------------------------------------------------------------------
template <int CIN, int COUT>
__global__ __launch_bounds__(256) void conv_gemm(const float* __restrict__ xin,
                                                 const float* __restrict__ ss,
                                                 const float* __restrict__ W,
                                                 float* __restrict__ y) {
    __shared__ float Wl[64][CIN + 1];
    __shared__ float Xl[32][132];

    const int tid = threadIdx.x;
    const int nb  = blockIdx.x * 128;
    const int ob  = blockIdx.y * 64;
    const int b   = blockIdx.z;

#pragma unroll
    for (int i = 0; i < CIN / 4; ++i) {
        int l = i * 256 + tid;
        int o = l / CIN, c = l % CIN;
        Wl[o][c] = W[(size_t)(ob + o) * CIN + c];
    }

    const int o0 = (tid >> 4) * 4;
    const int n0 = (tid & 15) * 8;

    float acc[4][8];
#pragma unroll
    for (int i = 0; i < 4; ++i)
#pragma unroll
        for (int j = 0; j < 8; ++j) acc[i][j] = 0.f;

    const int n4 = (tid & 31) * 4;
    const int kk0 = tid >> 5;

    for (int kc = 0; kc < CIN; kc += 32) {
        __syncthreads();
        const float* xbase = xin + ((size_t)(b * CIN + kc)) * NPTS;
#pragma unroll
        for (int i = 0; i < 4; ++i) {
            int kk = kk0 + i * 8;
            int ng = nb + n4;
            float4 v = make_float4(0.f, 0.f, 0.f, 0.f);
            if (ng + 4 <= NPTS) {
                v = *(const float4*)(xbase + (size_t)kk * NPTS + ng);
                float sc = ss[kc + kk], sh = ss[256 + kc + kk];
                v.x = fmaxf(fmaf(v.x, sc, sh), 0.f);
                v.y = fmaxf(fmaf(v.y, sc, sh), 0.f);
                v.z = fmaxf(fmaf(v.z, sc, sh), 0.f);
                v.w = fmaxf(fmaf(v.w, sc, sh), 0.f);
            }
            *(float4*)&Xl[kk][n4] = v;
        }
        __syncthreads();
#pragma unroll
        for (int k = 0; k < 32; ++k) {
            float w0 = Wl[o0 + 0][kc + k];
            float w1 = Wl[o0 + 1][kc + k];
            float w2 = Wl[o0 + 2][kc + k];
            float w3 = Wl[o0 + 3][kc + k];
            float4 xa = *(const float4*)&Xl[k][n0];
            float4 xb = *(const float4*)&Xl[k][n0 + 4];
            float xv[8] = {xa.x, xa.y, xa.z, xa.w, xb.x, xb.y, xb.z, xb.w};
#pragma unroll
            for (int j = 0; j < 8; ++j) {
                acc[0][j] = fmaf(w0, xv[j], acc[0][j]);
                acc[1][j] = fmaf(w1, xv[j], acc[1][j]);
                acc[2][j] = fmaf(w2, xv[j], acc[2][j]);
                acc[3][j] = fmaf(w3, xv[j], acc[3][j]);
            }
        }
    }

    const int ng = nb + n0;
#pragma unroll
    for (int i = 0; i < 4; ++i) {
        float* row = y + ((size_t)(b * COUT + ob + o0 + i)) * NPTS + ng;
        if (ng + 8 <= NPTS) {
            *(float4*)row       = make_float4(acc[i][0], acc[i][1], acc[i][2], acc[i][3]);
            *(float4*)(row + 4) = make_float4(acc[i][4], acc[i][5], acc[i][6], acc[i][7]);
        } else {
#pragma unroll
            for (int j = 0; j < 8; ++j)
                if (ng + j < NPTS) row[j] = acc[i][j];
        }
    }
}

// ---------------------------------------------------------------------------
// Per-channel sum / sumsq over (batch, points)  -> stats[c], stats[C+c]
// ---------------------------------------------------------------------------
__global__ void chan_stats(const float* __restrict__ y, int C, float* __restrict__ stats) {
    int c = blockIdx.x, b = blockIdx.y, t = threadIdx.x;
    const float* p = y + ((size_t)(b * C + c)) * NPTS;
    float s = 0.f, q = 0.f;
    for (int n = t; n < NPTS; n += 256) {
        float v = p[n];
        s += v;
        q = fmaf(v, v, q);
    }
    for (int off = 32; off; off >>= 1) {
        s += __shfl_down(s, off);
        q += __shfl_down(q, off);
    }
    __shared__ float ls[4], lq[4];
    if ((t & 63) == 0) { ls[t >> 6] = s; lq[t >> 6] = q; }
    __syncthreads();
    if (t == 0) {
        atomicAdd(&stats[c],     ls[0] + ls[1] + ls[2] + ls[3]);
        atomicAdd(&stats[C + c], lq[0] + lq[1] + lq[2] + lq[3]);
    }
}

__global__ void bn_finalize(const float* __restrict__ stats, const float* __restrict__ g,
                            const float* __restrict__ bi, int C, float* __restrict__ ss) {
    int c = threadIdx.x;
    if (c < C) {
        float mu  = stats[c] * (1.f / NBN);
        float var = stats[C + c] * (1.f / NBN) - mu * mu;
        float r = rsqrtf(var + 1e-5f);
        float s = g[c] * r;
        ss[c] = s;
        ss[256 + c] = bi[c] - mu * s;
    }
}

// ---------------------------------------------------------------------------
// Per-batch channel sums of final features f = relu(bn(y4))
// ---------------------------------------------------------------------------
__global__ void fsum_ker(const float* __restrict__ y4, const float* __restrict__ ss,
                         float* __restrict__ fsumb) {
    int c = blockIdx.x, b = blockIdx.y, t = threadIdx.x;
    const float* p = y4 + ((size_t)(b * 256 + c)) * NPTS;
    float sc = ss[c], sh = ss[256 + c];
    float s = 0.f;
    for (int n = t; n < NPTS; n += 256) {
        float v = fmaf(p[n], sc, sh);
        s += fmaxf(v, 0.f);
    }
    for (int off = 32; off; off >>= 1) s += __shfl_down(s, off);
    __shared__ float ls[4];
    if ((t & 63) == 0) ls[t >> 6] = s;
    __syncthreads();
    if (t == 0) fsumb[b * 256 + c] = ls[0] + ls[1] + ls[2] + ls[3];
}

// ---------------------------------------------------------------------------
// Split-bf16 MFMA second moment: covP[chunk][b][tile] 128x128 += F F^T
// over CHUNK_PTS points.
// grid: (COV_CHUNKS, 3 tiles{(0,0),(1,1),(0,1)}, 16 batches) = 960 blocks.
// LDS XOR-swizzle (byte bits 5-6 ^= bits 8-9) kills the 4-way ds_write
// bank conflict between the q point-groups; involution applied on both
// the staging writes and the fragment reads.
// ---------------------------------------------------------------------------
__device__ __forceinline__ unsigned short bf_hi(float f) {
    return (unsigned short)(__float_as_uint(f) >> 16);      // truncate to bf16
}
__device__ __forceinline__ unsigned short bf_lo(float f) {
    float hf = __uint_as_float(__float_as_uint(f) & 0xFFFF0000u);
    return (unsigned short)(__float_as_uint(f - hf) >> 16); // residual as bf16
}
__device__ __forceinline__ int swz8(int byteoff) {
    return byteoff ^ (((byteoff >> 8) & 3) << 5);
}

__global__ __launch_bounds__(256) void cov_mfma(const float* __restrict__ y4,
                                                const float* __restrict__ ss,
                                                float* __restrict__ covP) {
    __shared__ unsigned short pan[2][2][4096];   // [panel][hi/lo][8 frag-tiles * 512]

    const int chunk = blockIdx.x;
    const int tile  = blockIdx.y;
    const int b     = blockIdx.z;
    const int ti = (tile == 1) ? 1 : 0;
    const int tj = (tile == 0) ? 0 : 1;
    const int npan = (tile == 2) ? 2 : 1;

    const int tid  = threadIdx.x;
    const int lane = tid & 63;
    const int w    = tid >> 6;
    const int wr   = w & 1, wc = w >> 1;

    const int n0c = chunk * CHUNK_PTS;

    f32x4 acc[4][4];
#pragma unroll
    for (int m = 0; m < 4; ++m)
#pragma unroll
        for (int n = 0; n < 4; ++n) acc[m][n] = (f32x4){0.f, 0.f, 0.f, 0.f};

    // staging assignment: 8 point-groups (4 pts) x 32 channel-bases
    const int g   = tid & 7;
    const int chb = tid >> 3;          // 0..31
    const int p4  = g * 4;             // point offset in 32-chunk
    const int q   = p4 >> 3, j0 = p4 & 7;

#pragma unroll 1
    for (int kk = 0; kk < COV_KK; ++kk) {        // 16*32 = 512 >= 500
        const int nbase = n0c + kk * 32;
        __syncthreads();
        for (int p = 0; p < npan; ++p) {
            const int pcb = (p ? tj : ti) * 128;
#pragma unroll
            for (int i = 0; i < 4; ++i) {
                const int ch = chb + 32 * i;
                float4 v = make_float4(0.f, 0.f, 0.f, 0.f);
                if (kk * 32 + p4 < CHUNK_PTS) {
                    v = *(const float4*)(y4 + ((size_t)(b * 256 + pcb + ch)) * NPTS + nbase + p4);
                    float sc = ss[pcb + ch], sh = ss[256 + pcb + ch];
                    v.x = fmaxf(fmaf(v.x, sc, sh), 0.f);
                    v.y = fmaxf(fmaf(v.y, sc, sh), 0.f);
                    v.z = fmaxf(fmaf(v.z, sc, sh), 0.f);
                    v.w = fmaxf(fmaf(v.w, sc, sh), 0.f);
                }
                ushort4v h4, l4;
                h4[0] = bf_hi(v.x); l4[0] = bf_lo(v.x);
                h4[1] = bf_hi(v.y); l4[1] = bf_lo(v.y);
                h4[2] = bf_hi(v.z); l4[2] = bf_lo(v.z);
                h4[3] = bf_hi(v.w); l4[3] = bf_lo(v.w);
                const int addr = (ch >> 4) * 512 + (q * 16 + (ch & 15)) * 8 + j0;
                const int sa = swz8(addr * 2) >> 1;
                *(ushort4v*)&pan[p][0][sa] = h4;
                *(ushort4v*)&pan[p][1][sa] = l4;
            }
        }
        __syncthreads();

        const unsigned short* Ah = pan[0][0];
        const unsigned short* Al = pan[0][1];
        const unsigned short* Bh = pan[npan - 1][0];
        const unsigned short* Bl = pan[npan - 1][1];

        bf16x8 ah[4], al[4], bh[4], bl[4];
#pragma unroll
        for (int m = 0; m < 4; ++m) {
            int t8 = (wr * 4 + m) * 512 + lane * 8;
            int sa = swz8(t8 * 2) >> 1;
            ah[m] = *(const bf16x8*)&Ah[sa];
            al[m] = *(const bf16x8*)&Al[sa];
        }
#pragma unroll
        for (int n = 0; n < 4; ++n) {
            int t8 = (wc * 4 + n) * 512 + lane * 8;
            int sa = swz8(t8 * 2) >> 1;
            bh[n] = *(const bf16x8*)&Bh[sa];
            bl[n] = *(const bf16x8*)&Bl[sa];
        }
#pragma unroll
        for (int m = 0; m < 4; ++m)
#pragma unroll
            for (int n = 0; n < 4; ++n) {
                acc[m][n] = __builtin_amdgcn_mfma_f32_16x16x32_bf16(ah[m], bh[n], acc[m][n], 0, 0, 0);
                acc[m][n] = __builtin_amdgcn_mfma_f32_16x16x32_bf16(ah[m], bl[n], acc[m][n], 0, 0, 0);
                acc[m][n] = __builtin_amdgcn_mfma_f32_16x16x32_bf16(al[m], bh[n], acc[m][n], 0, 0, 0);
            }
    }

    // epilogue: packed per-(chunk,b,tile) 128x128 partial buffer (no atomics)
    float* outp = covP + (((size_t)(chunk * NB + b) * 3 + tile) << 14);
    const int rowb = wr * 64;
    const int colb = wc * 64;
#pragma unroll
    for (int m = 0; m < 4; ++m)
#pragma unroll
        for (int n = 0; n < 4; ++n)
#pragma unroll
            for (int r = 0; r < 4; ++r) {
                int row = rowb + m * 16 + (lane >> 4) * 4 + r;
                int col = colb + n * 16 + (lane & 15);
                outp[(row << 7) + col] = acc[m][n][r];
            }
}

// ---------------------------------------------------------------------------
// cov = (sum_q covP[q])/N - m fbar^T - fbar m^T + m m^T ; mirror tile (1,0)
// covP layout: [chunk][b][tile 0:(0,0) 1:(1,1) 2:(0,1)][128][128]
// ---------------------------------------------------------------------------
__global__ void covfin_ker(const float* __restrict__ covP, const float* __restrict__ fsumb,
                           float* __restrict__ Y0, float* __restrict__ trace) {
    int r = blockIdx.x, b = blockIdx.y, c = threadIdx.x;
    float fbr = fsumb[b * 256 + r] * (1.f / NPTS);
    float fbc = fsumb[b * 256 + c] * (1.f / NPTS);
    float mr = 0.f, mc = 0.f;
    for (int q = 0; q < NB; ++q) {
        mr += fsumb[q * 256 + r];
        mc += fsumb[q * 256 + c];
    }
    mr *= (1.f / NBN);
    mc *= (1.f / NBN);
    int tile, rr, cc;
    if (r < 128 && c < 128)        { tile = 0; rr = r;       cc = c; }
    else if (r >= 128 && c >= 128) { tile = 1; rr = r - 128; cc = c - 128; }
    else if (r < 128)              { tile = 2; rr = r;       cc = c - 128; }   // (0,1)
    else                           { tile = 2; rr = c;       cc = r - 128; }   // (1,0) mirror
    size_t base = (((size_t)b * 3 + tile) << 14) + ((size_t)rr << 7) + cc;
    float m5 = 0.f;
#pragma unroll
    for (int q = 0; q < COV_CHUNKS; ++q)
        m5 += covP[(size_t)q * (NB * 3 * 16384) + base];
    float v = m5 * (1.f / NPTS) - fbr * mc - mr * fbc + mr * mc;
    Y0[((size_t)b << 16) + ((size_t)r << 8) + c] = v;
    if (c == r) atomicAdd(&trace[b], v);
}

__global__ void ns_init(float* __restrict__ Y0, float* __restrict__ Z0,
                        const float* __restrict__ trace) {
    int i = blockIdx.x * 256 + threadIdx.x;   // 16*65536 total
    int b = i >> 16, rc = i & 65535;
    float inv = 1.f / trace[b];
    Y0[i] *= inv;
    Z0[i] = ((rc >> 8) == (rc & 255)) ? 1.f : 0.f;
}

// ---------------------------------------------------------------------------
// 256x256 batched GEMM tile body: O = diag*I + scale*(A.B), 64x64 tiles
// ---------------------------------------------------------------------------
__device__ __forceinline__ void gemm_body(const float* __restrict__ Ab,
                                          const float* __restrict__ Bb,
                                          float* __restrict__ Ob,
                                          float scale, float diag, int tile, int t,
                                          float (*Al)[68], float (*Bl)[68]) {
    int tr = (tile >> 2) * 64, tc = (tile & 3) * 64;
    int r0 = (t & 15) * 4, c0 = (t >> 4) * 4;
    float acc[4][4];
#pragma unroll
    for (int i = 0; i < 4; ++i)
#pragma unroll
        for (int j = 0; j < 4; ++j) acc[i][j] = 0.f;

    for (int kc = 0; kc < 256; kc += 64) {
        __syncthreads();
#pragma unroll
        for (int i = 0; i < 16; ++i) {
            int l = i * 256 + t;
            int ra = l >> 6, ka = l & 63;
            Al[ka][ra] = Ab[(size_t)(tr + ra) * 256 + kc + ka];
            Bl[ra][ka] = Bb[(size_t)(kc + ra) * 256 + tc + ka];
        }
        __syncthreads();
#pragma unroll 8
        for (int k = 0; k < 64; ++k) {
            float4 a4 = *(const float4*)&Al[k][r0];
            float4 b4 = *(const float4*)&Bl[k][c0];
            float av[4] = {a4.x, a4.y, a4.z, a4.w};
            float bv[4] = {b4.x, b4.y, b4.z, b4.w};
#pragma unroll
            for (int i = 0; i < 4; ++i)
#pragma unroll
                for (int j = 0; j < 4; ++j)
                    acc[i][j] = fmaf(av[i], bv[j], acc[i][j]);
        }
    }
#pragma unroll
    for (int i = 0; i < 4; ++i)
#pragma unroll
        for (int j = 0; j < 4; ++j) {
            int r = tr + r0 + i, c = tc + c0 + j;
            float v = scale * acc[i][j] + ((r == c) ? diag : 0.f);
            Ob[(size_t)r * 256 + c] = v;
        }
}

__global__ __launch_bounds__(256) void ns_gemm(const float* __restrict__ A,
                                               const float* __restrict__ B,
                                               float* __restrict__ O,
                                               float scale, float diag) {
    __shared__ float Al[64][68], Bl[64][68];
    size_t off = (size_t)blockIdx.y << 16;
    gemm_body(A + off, B + off, O + off, scale, diag, blockIdx.x, threadIdx.x, Al, Bl);
}

__global__ __launch_bounds__(256) void ns_gemm_pair(const float* __restrict__ Y,
                                                    const float* __restrict__ Mm,
                                                    const float* __restrict__ Z,
                                                    float* __restrict__ Yn,
                                                    float* __restrict__ Zn) {
    __shared__ float Al[64][68], Bl[64][68];
    size_t off = (size_t)blockIdx.y << 16;
    if (blockIdx.z == 0)
        gemm_body(Y + off, Mm + off, Yn + off, 0.5f, 0.f, blockIdx.x, threadIdx.x, Al, Bl);
    else
        gemm_body(Mm + off, Z + off, Zn + off, 0.5f, 0.f, blockIdx.x, threadIdx.x, Al, Bl);
}

// ---------------------------------------------------------------------------
// FC: outpre[b,o] += sum_k sqrt(trace[b])*Yf[b,k] * Wfc[o,k]
// ---------------------------------------------------------------------------
__global__ __launch_bounds__(256) void fc_ker(const float* __restrict__ Yf,
                                              const float* __restrict__ trace,
                                              const float* __restrict__ Wfc,
                                              float* __restrict__ outpre) {
    int kc = blockIdx.x;
    int ot = blockIdx.y;
    int t = threadIdx.x;
    __shared__ float Wl[64][129];
    __shared__ float Vl[16][129];
#pragma unroll
    for (int i = 0; i < 32; ++i) {
        int l = i * 256 + t;
        int o = l >> 7, k = l & 127;
        Wl[o][k] = Wfc[(size_t)(ot * 64 + o) * 65536 + kc * 128 + k];
    }
#pragma unroll
    for (int i = 0; i < 8; ++i) {
        int l = i * 256 + t;
        int bb = l >> 7, k = l & 127;
        Vl[bb][k] = sqrtf(trace[bb]) * Yf[((size_t)bb << 16) + kc * 128 + k];
    }
    __syncthreads();
    int ol = t & 63, bg = t >> 6;
    float a0 = 0.f, a1 = 0.f, a2 = 0.f, a3 = 0.f;
    for (int k = 0; k < 128; ++k) {
        float w = Wl[ol][k];
        a0 = fmaf(w, Vl[bg * 4 + 0][k], a0);
        a1 = fmaf(w, Vl[bg * 4 + 1][k], a1);
        a2 = fmaf(w, Vl[bg * 4 + 2][k], a2);
        a3 = fmaf(w, Vl[bg * 4 + 3][k], a3);
    }
    int o = ot * 64 + ol;
    atomicAdd(&outpre[(bg * 4 + 0) * 256 + o], a0);
    atomicAdd(&outpre[(bg * 4 + 1) * 256 + o], a1);
    atomicAdd(&outpre[(bg * 4 + 2) * 256 + o], a2);
    atomicAdd(&outpre[(bg * 4 + 3) * 256 + o], a3);
}

__global__ void norm_ker(const float* __restrict__ outpre, const float* __restrict__ bfc,
                         float* __restrict__ dout) {
    int b = blockIdx.x, t = threadIdx.x;
    float v = outpre[b * 256 + t] + bfc[t];
    float q = v * v;
    for (int off = 32; off; off >>= 1) q += __shfl_xor(q, off);
    __shared__ float lq[4];
    __shared__ float snorm;
    if ((t & 63) == 0) lq[t >> 6] = q;
    __syncthreads();
    if (t == 0) snorm = fmaxf(sqrtf(lq[0] + lq[1] + lq[2] + lq[3]), 1e-12f);
    __syncthreads();
    dout[b * 256 + t] = v / snorm;
}

// ---------------------------------------------------------------------------
extern "C" void kernel_launch(void* const* d_in, const int* in_sizes, int n_in,
                              void* d_out, int out_size, void* d_ws, size_t ws_size,
                              hipStream_t stream) {
    (void)in_sizes; (void)n_in; (void)out_size; (void)ws_size;
    const float* pts = (const float*)d_in[0];
    const float* Wm[5]; const float* gm[5]; const float* bm[5];
    for (int i = 0; i < 5; ++i) {
        Wm[i] = (const float*)d_in[1 + 3 * i];
        gm[i] = (const float*)d_in[2 + 3 * i];
        bm[i] = (const float*)d_in[3 + 3 * i];
    }
    const float* Wfc = (const float*)d_in[16];
    const float* bfc = (const float*)d_in[17];

    float* ws     = (float*)d_ws;
    float* stats  = ws;                  // 2560
    float* fsumb  = ws + 2560;           // 4096
    float* trace  = ws + 6656;           // 16
    float* outpre = ws + 6672;           // 4096
    float* ss     = ws + 10768;          // 2560
    float* R      = ws + 16384;          // 256ch fp32: 40,960,000 floats (y4)
    float* P      = R;                   // 64ch view (L0/L2 out)
    float* Q      = R + (size_t)NB * 256 * NPTS;   // 128ch: 20,480,000 floats
    // cov partials alias the (then-dead) Q region:
    // 20 chunks * 16 b * 3 tiles * 16384 = 15,728,640 floats < 20.48M
    float* covP   = Q;
    // NS buffers alias the (then-dead) R region (R dead after cov_mfma/fsum):
    float* Y0     = R;
    float* Y1     = Y0 + 1048576;
    float* Z0     = Y1 + 1048576;
    float* Z1     = Z0 + 1048576;
    float* Mb     = Z1 + 1048576;        // 5.24M floats << 40.96M of R

    hipMemsetAsync(ws, 0, 16384 * sizeof(float), stream);

    // Layer 0 (3 -> 64)
    conv0_ker<<<dim3(NBN / 256), dim3(256), 0, stream>>>(pts, Wm[0], P);
    chan_stats<<<dim3(64, NB), dim3(256), 0, stream>>>(P, 64, stats);
    bn_finalize<<<dim3(1), dim3(256), 0, stream>>>(stats, gm[0], bm[0], 64, ss);
    // Layer 1 (64 -> 64)
    conv_gemm<64, 64><<<dim3(79, 1, NB), dim3(256), 0, stream>>>(P, ss, Wm[1], Q);
    chan_stats<<<dim3(64, NB), dim3(256), 0, stream>>>(Q, 64, stats + 512);
    bn_finalize<<<dim3(1), dim3(256), 0, stream>>>(stats + 512, gm[1], bm[1], 64, ss + 512);
    // Layer 2 (64 -> 64)
    conv_gemm<64, 64><<<dim3(79, 1, NB), dim3(256), 0, stream>>>(Q, ss + 512, Wm[2], P);
    chan_stats<<<dim3(64, NB), dim3(256), 0, stream>>>(P, 64, stats + 1024);
    bn_finalize<<<dim3(1), dim3(256), 0, stream>>>(stats + 1024, gm[2], bm[2], 64, ss + 1024);
    // Layer 3 (64 -> 128)
    conv_gemm<64, 128><<<dim3(79, 2, NB), dim3(256), 0, stream>>>(P, ss + 1024, Wm[3], Q);
    chan_stats<<<dim3(128, NB), dim3(256), 0, stream>>>(Q, 128, stats + 1536);
    bn_finalize<<<dim3(1), dim3(256), 0, stream>>>(stats + 1536, gm[3], bm[3], 128, ss + 1536);
    // Layer 4 (128 -> 256); writes R (P is dead now)
    conv_gemm<128, 256><<<dim3(79, 4, NB), dim3(256), 0, stream>>>(Q, ss + 1536, Wm[4], R);
    chan_stats<<<dim3(256, NB), dim3(256), 0, stream>>>(R, 256, stats + 2048);
    bn_finalize<<<dim3(1), dim3(256), 0, stream>>>(stats + 2048, gm[4], bm[4], 256, ss + 2048);

    // Covariance path (Q dead; its region hosts covP; NS buffers go to R
    // which dies after fsum/cov_mfma complete)
    fsum_ker<<<dim3(256, NB), dim3(256), 0, stream>>>(R, ss + 2048, fsumb);
    cov_mfma<<<dim3(COV_CHUNKS, 3, NB), dim3(256), 0, stream>>>(R, ss + 2048, covP);
    covfin_ker<<<dim3(256, NB), dim3(256), 0, stream>>>(covP, fsumb, Y0, trace);
    ns_init<<<dim3(4096), dim3(256), 0, stream>>>(Y0, Z0, trace);

    // Newton–Schulz iterations for principal sqrt
    float* Yc = Y0; float* Zc = Z0; float* Yn = Y1; float* Zn = Z1;
    for (int it = 0; it < NS_ITERS; ++it) {
        ns_gemm<<<dim3(16, NB), dim3(256), 0, stream>>>(Zc, Yc, Mb, -1.f, 3.f);
        ns_gemm_pair<<<dim3(16, NB, 2), dim3(256), 0, stream>>>(Yc, Mb, Zc, Yn, Zn);
        float* ty = Yc; Yc = Yn; Yn = ty;
        float* tz = Zc; Zc = Zn; Zn = tz;
    }

    fc_ker<<<dim3(512, 4), dim3(256), 0, stream>>>(Yc, trace, Wfc, outpre);
    norm_ker<<<dim3(NB), dim3(256), 0, stream>>>(outpre, bfc, (float*)d_out);
}

// Round 2
// 2281.495 us; speedup vs baseline: 1.1335x; 1.0821x over previous
//
#include <hip/hip_runtime.h>
#include <cmath>

constexpr int NB   = 16;      // batch
constexpr int NPTS = 10000;   // points per batch
constexpr int NBN  = NB * NPTS;   // 160000
constexpr int NS_ITERS = 18;
constexpr int COV_CHUNKS = 20;    // 500 points each
constexpr int CHUNK_PTS  = 500;
constexpr int COV_KK     = 16;    // 16*32 = 512 >= 500

typedef __bf16 bf16x8 __attribute__((ext_vector_type(8)));
typedef _Float16 f16x8 __attribute__((ext_vector_type(8)));
typedef float  f32x4  __attribute__((ext_vector_type(4)));
typedef unsigned short ushort4v __attribute__((ext_vector_type(4)));
typedef unsigned short ushort8v __attribute__((ext_vector_type(8)));

// ---------------------------------------------------------------------------
// Layer 0: 3 -> 64, no input BN
// ---------------------------------------------------------------------------
__global__ __launch_bounds__(256) void conv0_ker(const float* __restrict__ pts,
                                                 const float* __restrict__ W,
                                                 float* __restrict__ y) {
    int g = blockIdx.x * 256 + threadIdx.x;          // 0..159999
    int b = g / NPTS;
    int n = g - b * NPTS;
    float p0 = pts[3 * (size_t)g + 0];
    float p1 = pts[3 * (size_t)g + 1];
    float p2 = pts[3 * (size_t)g + 2];
    float* yp = y + ((size_t)b * 64) * NPTS + n;
    for (int o = 0; o < 64; ++o) {
        float v = W[3 * o] * p0 + W[3 * o + 1] * p1 + W[3 * o + 2] * p2;
        yp[(size_t)o * NPTS] = v;
    }
}

// ---------------------------------------------------------------------------
// split-fp16 helpers (hi = fp16(v), lo = fp16(v - hi)): 3-MFMA product keeps
// ~2^-22 relative accuracy, effectively fp32 for this pipeline.
// ---------------------------------------------------------------------------
__device__ __forceinline__ unsigned short f2h(float f) {
    return __builtin_bit_cast(unsigned short, (_Float16)f);
}
__device__ __forceinline__ float hres(float f) {
    return f - (float)(_Float16)f;
}
// LDS XOR-swizzle on ushort index (byte bits 5-6 ^= bits 8-9), 8-us aligned
__device__ __forceinline__ int swzu(int us) {
    return us ^ (((us >> 7) & 3) << 4);
}

// ---------------------------------------------------------------------------
// MFMA conv layer: y[b, ob+o, n] = sum_c W[ob+o, c] * relu(bn(x[b, c, n]))
// Block tile: OTILE x 128 points; waves 2x2 (OTILE=128) or 1x4 (OTILE=64).
// Panels staged in cov_mfma fragment layout: tile(first>>4)*512 +
// (q*16 + (first&15))*8 + j, q=k>>3, j=k&7; XOR-swizzled.
// ---------------------------------------------------------------------------
template <int CIN, int COUT, int OTILE>
__global__ __launch_bounds__(256) void conv_mfma(const float* __restrict__ xin,
                                                 const float* __restrict__ ss,
                                                 const float* __restrict__ W,
                                                 float* __restrict__ y) {
    constexpr int OT = OTILE / 16;
    constexpr int WM = 4;
    constexpr int WN = (OTILE == 128) ? 4 : 2;
    __shared__ unsigned short Xp[2][8 * 512];
    __shared__ unsigned short Wp[2][OT * 512];

    const int tid  = threadIdx.x;
    const int lane = tid & 63;
    const int w    = tid >> 6;
    const int wr   = (OTILE == 128) ? (w & 1) : 0;
    const int wc   = (OTILE == 128) ? (w >> 1) : w;

    const int nb = blockIdx.x * 128;
    const int ob = blockIdx.y * OTILE;
    const int b  = blockIdx.z;

    f32x4 acc[WM][WN];
#pragma unroll
    for (int m = 0; m < WM; ++m)
#pragma unroll
        for (int n = 0; n < WN; ++n) acc[m][n] = (f32x4){0.f, 0.f, 0.f, 0.f};

    const int xn = tid & 127;
    const int th = tid >> 7;
    const bool nok = (nb + xn) < NPTS;

#pragma unroll 1
    for (int kc = 0; kc < CIN; kc += 32) {
        __syncthreads();
        // ---- stage W[ob..ob+OTILE)[kc..kc+32) as split-fp16 A panels ----
#pragma unroll
        for (int i = 0; i < OTILE / 32; ++i) {
            int l = i * 256 + tid;
            int o = l >> 3, k4 = (l & 7) << 2;
            float4 v = *(const float4*)(W + (size_t)(ob + o) * CIN + kc + k4);
            ushort4v h4, l4;
            h4[0] = f2h(v.x); l4[0] = f2h(hres(v.x));
            h4[1] = f2h(v.y); l4[1] = f2h(hres(v.y));
            h4[2] = f2h(v.z); l4[2] = f2h(hres(v.z));
            h4[3] = f2h(v.w); l4[3] = f2h(hres(v.w));
            int us = swzu((o >> 4) * 512 + ((k4 >> 3) * 16 + (o & 15)) * 8 + (k4 & 7));
            *(ushort4v*)&Wp[0][us] = h4;
            *(ushort4v*)&Wp[1][us] = l4;
        }
        // ---- stage relu(bn(x))[kc..kc+32)[nb..nb+128) as split-fp16 B panels ----
#pragma unroll
        for (int qq = 0; qq < 2; ++qq) {
            int q = th * 2 + qq;
            const float* xb = xin + ((size_t)(b * CIN + kc + q * 8)) * NPTS + nb + xn;
            float f[8];
#pragma unroll
            for (int j = 0; j < 8; ++j) {
                float v = nok ? xb[(size_t)j * NPTS] : 0.f;
                int c = kc + q * 8 + j;
                f[j] = fmaxf(fmaf(v, ss[c], ss[256 + c]), 0.f);
            }
            ushort8v h8, l8;
#pragma unroll
            for (int j = 0; j < 8; ++j) {
                h8[j] = f2h(f[j]);
                l8[j] = f2h(hres(f[j]));
            }
            int us = swzu((xn >> 4) * 512 + (q * 16 + (xn & 15)) * 8);
            *(ushort8v*)&Xp[0][us] = h8;
            *(ushort8v*)&Xp[1][us] = l8;
        }
        __syncthreads();

        f16x8 ah[WM], al[WM], bh[WN], bl[WN];
#pragma unroll
        for (int m = 0; m < WM; ++m) {
            int us = swzu((wr * WM + m) * 512 + lane * 8);
            ah[m] = *(const f16x8*)&Wp[0][us];
            al[m] = *(const f16x8*)&Wp[1][us];
        }
#pragma unroll
        for (int n = 0; n < WN; ++n) {
            int us = swzu((wc * WN + n) * 512 + lane * 8);
            bh[n] = *(const f16x8*)&Xp[0][us];
            bl[n] = *(const f16x8*)&Xp[1][us];
        }
#pragma unroll
        for (int m = 0; m < WM; ++m)
#pragma unroll
            for (int n = 0; n < WN; ++n) {
                acc[m][n] = __builtin_amdgcn_mfma_f32_16x16x32_f16(ah[m], bh[n], acc[m][n], 0, 0, 0);
                acc[m][n] = __builtin_amdgcn_mfma_f32_16x16x32_f16(ah[m], bl[n], acc[m][n], 0, 0, 0);
                acc[m][n] = __builtin_amdgcn_mfma_f32_16x16x32_f16(al[m], bh[n], acc[m][n], 0, 0, 0);
            }
    }

    // ---- epilogue ----
    const int ro = (lane >> 4) * 4;
    const int co = lane & 15;
#pragma unroll
    for (int m = 0; m < WM; ++m) {
        int o = ob + wr * (WM * 16) + m * 16 + ro;
#pragma unroll
        for (int n = 0; n < WN; ++n) {
            int col = nb + wc * (WN * 16) + n * 16 + co;
            if (col < NPTS) {
                float* yp = y + ((size_t)(b * COUT + o)) * NPTS + col;
#pragma unroll
                for (int r = 0; r < 4; ++r)
                    yp[(size_t)r * NPTS] = acc[m][n][r];
            }
        }
    }
}

// ---------------------------------------------------------------------------
// Per-channel sum / sumsq over (batch, points)  -> stats[c], stats[C+c]
// ---------------------------------------------------------------------------
__global__ void chan_stats(const float* __restrict__ y, int C, float* __restrict__ stats) {
    int c = blockIdx.x, b = blockIdx.y, t = threadIdx.x;
    const float* p = y + ((size_t)(b * C + c)) * NPTS;
    float s = 0.f, q = 0.f;
    for (int n = t; n < NPTS; n += 256) {
        float v = p[n];
        s += v;
        q = fmaf(v, v, q);
    }
    for (int off = 32; off; off >>= 1) {
        s += __shfl_down(s, off);
        q += __shfl_down(q, off);
    }
    __shared__ float ls[4], lq[4];
    if ((t & 63) == 0) { ls[t >> 6] = s; lq[t >> 6] = q; }
    __syncthreads();
    if (t == 0) {
        atomicAdd(&stats[c],     ls[0] + ls[1] + ls[2] + ls[3]);
        atomicAdd(&stats[C + c], lq[0] + lq[1] + lq[2] + lq[3]);
    }
}

__global__ void bn_finalize(const float* __restrict__ stats, const float* __restrict__ g,
                            const float* __restrict__ bi, int C, float* __restrict__ ss) {
    int c = threadIdx.x;
    if (c < C) {
        float mu  = stats[c] * (1.f / NBN);
        float var = stats[C + c] * (1.f / NBN) - mu * mu;
        float r = rsqrtf(var + 1e-5f);
        float s = g[c] * r;
        ss[c] = s;
        ss[256 + c] = bi[c] - mu * s;
    }
}

// ---------------------------------------------------------------------------
// Per-batch channel sums of final features f = relu(bn(y4))
// ---------------------------------------------------------------------------
__global__ void fsum_ker(const float* __restrict__ y4, const float* __restrict__ ss,
                         float* __restrict__ fsumb) {
    int c = blockIdx.x, b = blockIdx.y, t = threadIdx.x;
    const float* p = y4 + ((size_t)(b * 256 + c)) * NPTS;
    float sc = ss[c], sh = ss[256 + c];
    float s = 0.f;
    for (int n = t; n < NPTS; n += 256) {
        float v = fmaf(p[n], sc, sh);
        s += fmaxf(v, 0.f);
    }
    for (int off = 32; off; off >>= 1) s += __shfl_down(s, off);
    __shared__ float ls[4];
    if ((t & 63) == 0) ls[t >> 6] = s;
    __syncthreads();
    if (t == 0) fsumb[b * 256 + c] = ls[0] + ls[1] + ls[2] + ls[3];
}

// ---------------------------------------------------------------------------
// Split-bf16 MFMA second moment: covP[chunk][b][tile] 128x128 += F F^T
// over CHUNK_PTS points.
// grid: (COV_CHUNKS, 3 tiles{(0,0),(1,1),(0,1)}, 16 batches) = 960 blocks.
// ---------------------------------------------------------------------------
__device__ __forceinline__ unsigned short bf_hi(float f) {
    return (unsigned short)(__float_as_uint(f) >> 16);      // truncate to bf16
}
__device__ __forceinline__ unsigned short bf_lo(float f) {
    float hf = __uint_as_float(__float_as_uint(f) & 0xFFFF0000u);
    return (unsigned short)(__float_as_uint(f - hf) >> 16); // residual as bf16
}
__device__ __forceinline__ int swz8(int byteoff) {
    return byteoff ^ (((byteoff >> 8) & 3) << 5);
}

__global__ __launch_bounds__(256) void cov_mfma(const float* __restrict__ y4,
                                                const float* __restrict__ ss,
                                                float* __restrict__ covP) {
    __shared__ unsigned short pan[2][2][4096];   // [panel][hi/lo][8 frag-tiles * 512]

    const int chunk = blockIdx.x;
    const int tile  = blockIdx.y;
    const int b     = blockIdx.z;
    const int ti = (tile == 1) ? 1 : 0;
    const int tj = (tile == 0) ? 0 : 1;
    const int npan = (tile == 2) ? 2 : 1;

    const int tid  = threadIdx.x;
    const int lane = tid & 63;
    const int w    = tid >> 6;
    const int wr   = w & 1, wc = w >> 1;

    const int n0c = chunk * CHUNK_PTS;

    f32x4 acc[4][4];
#pragma unroll
    for (int m = 0; m < 4; ++m)
#pragma unroll
        for (int n = 0; n < 4; ++n) acc[m][n] = (f32x4){0.f, 0.f, 0.f, 0.f};

    // staging assignment: 8 point-groups (4 pts) x 32 channel-bases
    const int g   = tid & 7;
    const int chb = tid >> 3;          // 0..31
    const int p4  = g * 4;             // point offset in 32-chunk
    const int q   = p4 >> 3, j0 = p4 & 7;

#pragma unroll 1
    for (int kk = 0; kk < COV_KK; ++kk) {        // 16*32 = 512 >= 500
        const int nbase = n0c + kk * 32;
        __syncthreads();
        for (int p = 0; p < npan; ++p) {
            const int pcb = (p ? tj : ti) * 128;
#pragma unroll
            for (int i = 0; i < 4; ++i) {
                const int ch = chb + 32 * i;
                float4 v = make_float4(0.f, 0.f, 0.f, 0.f);
                if (kk * 32 + p4 < CHUNK_PTS) {
                    v = *(const float4*)(y4 + ((size_t)(b * 256 + pcb + ch)) * NPTS + nbase + p4);
                    float sc = ss[pcb + ch], sh = ss[256 + pcb + ch];
                    v.x = fmaxf(fmaf(v.x, sc, sh), 0.f);
                    v.y = fmaxf(fmaf(v.y, sc, sh), 0.f);
                    v.z = fmaxf(fmaf(v.z, sc, sh), 0.f);
                    v.w = fmaxf(fmaf(v.w, sc, sh), 0.f);
                }
                ushort4v h4, l4;
                h4[0] = bf_hi(v.x); l4[0] = bf_lo(v.x);
                h4[1] = bf_hi(v.y); l4[1] = bf_lo(v.y);
                h4[2] = bf_hi(v.z); l4[2] = bf_lo(v.z);
                h4[3] = bf_hi(v.w); l4[3] = bf_lo(v.w);
                const int addr = (ch >> 4) * 512 + (q * 16 + (ch & 15)) * 8 + j0;
                const int sa = swz8(addr * 2) >> 1;
                *(ushort4v*)&pan[p][0][sa] = h4;
                *(ushort4v*)&pan[p][1][sa] = l4;
            }
        }
        __syncthreads();

        const unsigned short* Ah = pan[0][0];
        const unsigned short* Al = pan[0][1];
        const unsigned short* Bh = pan[npan - 1][0];
        const unsigned short* Bl = pan[npan - 1][1];

        bf16x8 ah[4], al[4], bh[4], bl[4];
#pragma unroll
        for (int m = 0; m < 4; ++m) {
            int t8 = (wr * 4 + m) * 512 + lane * 8;
            int sa = swz8(t8 * 2) >> 1;
            ah[m] = *(const bf16x8*)&Ah[sa];
            al[m] = *(const bf16x8*)&Al[sa];
        }
#pragma unroll
        for (int n = 0; n < 4; ++n) {
            int t8 = (wc * 4 + n) * 512 + lane * 8;
            int sa = swz8(t8 * 2) >> 1;
            bh[n] = *(const bf16x8*)&Bh[sa];
            bl[n] = *(const bf16x8*)&Bl[sa];
        }
#pragma unroll
        for (int m = 0; m < 4; ++m)
#pragma unroll
            for (int n = 0; n < 4; ++n) {
                acc[m][n] = __builtin_amdgcn_mfma_f32_16x16x32_bf16(ah[m], bh[n], acc[m][n], 0, 0, 0);
                acc[m][n] = __builtin_amdgcn_mfma_f32_16x16x32_bf16(ah[m], bl[n], acc[m][n], 0, 0, 0);
                acc[m][n] = __builtin_amdgcn_mfma_f32_16x16x32_bf16(al[m], bh[n], acc[m][n], 0, 0, 0);
            }
    }

    // epilogue: packed per-(chunk,b,tile) 128x128 partial buffer (no atomics)
    float* outp = covP + (((size_t)(chunk * NB + b) * 3 + tile) << 14);
    const int rowb = wr * 64;
    const int colb = wc * 64;
#pragma unroll
    for (int m = 0; m < 4; ++m)
#pragma unroll
        for (int n = 0; n < 4; ++n)
#pragma unroll
            for (int r = 0; r < 4; ++r) {
                int row = rowb + m * 16 + (lane >> 4) * 4 + r;
                int col = colb + n * 16 + (lane & 15);
                outp[(row << 7) + col] = acc[m][n][r];
            }
}

// ---------------------------------------------------------------------------
// cov = (sum_q covP[q])/N - m fbar^T - fbar m^T + m m^T ; mirror tile (1,0)
// covP layout: [chunk][b][tile 0:(0,0) 1:(1,1) 2:(0,1)][128][128]
// ---------------------------------------------------------------------------
__global__ void covfin_ker(const float* __restrict__ covP, const float* __restrict__ fsumb,
                           float* __restrict__ Y0, float* __restrict__ trace) {
    int r = blockIdx.x, b = blockIdx.y, c = threadIdx.x;
    float fbr = fsumb[b * 256 + r] * (1.f / NPTS);
    float fbc = fsumb[b * 256 + c] * (1.f / NPTS);
    float mr = 0.f, mc = 0.f;
    for (int q = 0; q < NB; ++q) {
        mr += fsumb[q * 256 + r];
        mc += fsumb[q * 256 + c];
    }
    mr *= (1.f / NBN);
    mc *= (1.f / NBN);
    int tile, rr, cc;
    if (r < 128 && c < 128)        { tile = 0; rr = r;       cc = c; }
    else if (r >= 128 && c >= 128) { tile = 1; rr = r - 128; cc = c - 128; }
    else if (r < 128)              { tile = 2; rr = r;       cc = c - 128; }   // (0,1)
    else                           { tile = 2; rr = c;       cc = r - 128; }   // (1,0) mirror
    size_t base = (((size_t)b * 3 + tile) << 14) + ((size_t)rr << 7) + cc;
    float m5 = 0.f;
#pragma unroll
    for (int q = 0; q < COV_CHUNKS; ++q)
        m5 += covP[(size_t)q * (NB * 3 * 16384) + base];
    float v = m5 * (1.f / NPTS) - fbr * mc - mr * fbc + mr * mc;
    Y0[((size_t)b << 16) + ((size_t)r << 8) + c] = v;
    if (c == r) atomicAdd(&trace[b], v);
}

__global__ void ns_init(float* __restrict__ Y0, float* __restrict__ Z0,
                        const float* __restrict__ trace) {
    int i = blockIdx.x * 256 + threadIdx.x;   // 16*65536 total
    int b = i >> 16, rc = i & 65535;
    float inv = 1.f / trace[b];
    Y0[i] *= inv;
    Z0[i] = ((rc >> 8) == (rc & 255)) ? 1.f : 0.f;
}

// ---------------------------------------------------------------------------
// 256x256 batched GEMM tile body: O = diag*I + scale*(A.B), 64x64 tiles
// ---------------------------------------------------------------------------
__device__ __forceinline__ void gemm_body(const float* __restrict__ Ab,
                                          const float* __restrict__ Bb,
                                          float* __restrict__ Ob,
                                          float scale, float diag, int tile, int t,
                                          float (*Al)[68], float (*Bl)[68]) {
    int tr = (tile >> 2) * 64, tc = (tile & 3) * 64;
    int r0 = (t & 15) * 4, c0 = (t >> 4) * 4;
    float acc[4][4];
#pragma unroll
    for (int i = 0; i < 4; ++i)
#pragma unroll
        for (int j = 0; j < 4; ++j) acc[i][j] = 0.f;

    for (int kc = 0; kc < 256; kc += 64) {
        __syncthreads();
#pragma unroll
        for (int i = 0; i < 16; ++i) {
            int l = i * 256 + t;
            int ra = l >> 6, ka = l & 63;
            Al[ka][ra] = Ab[(size_t)(tr + ra) * 256 + kc + ka];
            Bl[ra][ka] = Bb[(size_t)(kc + ra) * 256 + tc + ka];
        }
        __syncthreads();
#pragma unroll 8
        for (int k = 0; k < 64; ++k) {
            float4 a4 = *(const float4*)&Al[k][r0];
            float4 b4 = *(const float4*)&Bl[k][c0];
            float av[4] = {a4.x, a4.y, a4.z, a4.w};
            float bv[4] = {b4.x, b4.y, b4.z, b4.w};
#pragma unroll
            for (int i = 0; i < 4; ++i)
#pragma unroll
                for (int j = 0; j < 4; ++j)
                    acc[i][j] = fmaf(av[i], bv[j], acc[i][j]);
        }
    }
#pragma unroll
    for (int i = 0; i < 4; ++i)
#pragma unroll
        for (int j = 0; j < 4; ++j) {
            int r = tr + r0 + i, c = tc + c0 + j;
            float v = scale * acc[i][j] + ((r == c) ? diag : 0.f);
            Ob[(size_t)r * 256 + c] = v;
        }
}

__global__ __launch_bounds__(256) void ns_gemm(const float* __restrict__ A,
                                               const float* __restrict__ B,
                                               float* __restrict__ O,
                                               float scale, float diag) {
    __shared__ float Al[64][68], Bl[64][68];
    size_t off = (size_t)blockIdx.y << 16;
    gemm_body(A + off, B + off, O + off, scale, diag, blockIdx.x, threadIdx.x, Al, Bl);
}

__global__ __launch_bounds__(256) void ns_gemm_pair(const float* __restrict__ Y,
                                                    const float* __restrict__ Mm,
                                                    const float* __restrict__ Z,
                                                    float* __restrict__ Yn,
                                                    float* __restrict__ Zn) {
    __shared__ float Al[64][68], Bl[64][68];
    size_t off = (size_t)blockIdx.y << 16;
    if (blockIdx.z == 0)
        gemm_body(Y + off, Mm + off, Yn + off, 0.5f, 0.f, blockIdx.x, threadIdx.x, Al, Bl);
    else
        gemm_body(Mm + off, Z + off, Zn + off, 0.5f, 0.f, blockIdx.x, threadIdx.x, Al, Bl);
}

// ---------------------------------------------------------------------------
// FC: outpre[b,o] += sum_k sqrt(trace[b])*Yf[b,k] * Wfc[o,k]
// ---------------------------------------------------------------------------
__global__ __launch_bounds__(256) void fc_ker(const float* __restrict__ Yf,
                                              const float* __restrict__ trace,
                                              const float* __restrict__ Wfc,
                                              float* __restrict__ outpre) {
    int kc = blockIdx.x;
    int ot = blockIdx.y;
    int t = threadIdx.x;
    __shared__ float Wl[64][129];
    __shared__ float Vl[16][129];
#pragma unroll
    for (int i = 0; i < 32; ++i) {
        int l = i * 256 + t;
        int o = l >> 7, k = l & 127;
        Wl[o][k] = Wfc[(size_t)(ot * 64 + o) * 65536 + kc * 128 + k];
    }
#pragma unroll
    for (int i = 0; i < 8; ++i) {
        int l = i * 256 + t;
        int bb = l >> 7, k = l & 127;
        Vl[bb][k] = sqrtf(trace[bb]) * Yf[((size_t)bb << 16) + kc * 128 + k];
    }
    __syncthreads();
    int ol = t & 63, bg = t >> 6;
    float a0 = 0.f, a1 = 0.f, a2 = 0.f, a3 = 0.f;
    for (int k = 0; k < 128; ++k) {
        float w = Wl[ol][k];
        a0 = fmaf(w, Vl[bg * 4 + 0][k], a0);
        a1 = fmaf(w, Vl[bg * 4 + 1][k], a1);
        a2 = fmaf(w, Vl[bg * 4 + 2][k], a2);
        a3 = fmaf(w, Vl[bg * 4 + 3][k], a3);
    }
    int o = ot * 64 + ol;
    atomicAdd(&outpre[(bg * 4 + 0) * 256 + o], a0);
    atomicAdd(&outpre[(bg * 4 + 1) * 256 + o], a1);
    atomicAdd(&outpre[(bg * 4 + 2) * 256 + o], a2);
    atomicAdd(&outpre[(bg * 4 + 3) * 256 + o], a3);
}

__global__ void norm_ker(const float* __restrict__ outpre, const float* __restrict__ bfc,
                         float* __restrict__ dout) {
    int b = blockIdx.x, t = threadIdx.x;
    float v = outpre[b * 256 + t] + bfc[t];
    float q = v * v;
    for (int off = 32; off; off >>= 1) q += __shfl_xor(q, off);
    __shared__ float lq[4];
    __shared__ float snorm;
    if ((t & 63) == 0) lq[t >> 6] = q;
    __syncthreads();
    if (t == 0) snorm = fmaxf(sqrtf(lq[0] + lq[1] + lq[2] + lq[3]), 1e-12f);
    __syncthreads();
    dout[b * 256 + t] = v / snorm;
}

// ---------------------------------------------------------------------------
extern "C" void kernel_launch(void* const* d_in, const int* in_sizes, int n_in,
                              void* d_out, int out_size, void* d_ws, size_t ws_size,
                              hipStream_t stream) {
    (void)in_sizes; (void)n_in; (void)out_size; (void)ws_size;
    const float* pts = (const float*)d_in[0];
    const float* Wm[5]; const float* gm[5]; const float* bm[5];
    for (int i = 0; i < 5; ++i) {
        Wm[i] = (const float*)d_in[1 + 3 * i];
        gm[i] = (const float*)d_in[2 + 3 * i];
        bm[i] = (const float*)d_in[3 + 3 * i];
    }
    const float* Wfc = (const float*)d_in[16];
    const float* bfc = (const float*)d_in[17];

    float* ws     = (float*)d_ws;
    float* stats  = ws;                  // 2560
    float* fsumb  = ws + 2560;           // 4096
    float* trace  = ws + 6656;           // 16
    float* outpre = ws + 6672;           // 4096
    float* ss     = ws + 10768;          // 2560
    float* R      = ws + 16384;          // 256ch fp32: 40,960,000 floats (y4)
    float* P      = R;                   // 64ch view (L0/L2 out)
    float* Q      = R + (size_t)NB * 256 * NPTS;   // 128ch: 20,480,000 floats
    // cov partials alias the (then-dead) Q region:
    // 20 chunks * 16 b * 3 tiles * 16384 = 15,728,640 floats < 20.48M
    float* covP   = Q;
    // NS buffers alias the (then-dead) R region (R dead after cov_mfma/fsum):
    float* Y0     = R;
    float* Y1     = Y0 + 1048576;
    float* Z0     = Y1 + 1048576;
    float* Z1     = Z0 + 1048576;
    float* Mb     = Z1 + 1048576;        // 5.24M floats << 40.96M of R

    hipMemsetAsync(ws, 0, 16384 * sizeof(float), stream);

    // Layer 0 (3 -> 64)
    conv0_ker<<<dim3(NBN / 256), dim3(256), 0, stream>>>(pts, Wm[0], P);
    chan_stats<<<dim3(64, NB), dim3(256), 0, stream>>>(P, 64, stats);
    bn_finalize<<<dim3(1), dim3(256), 0, stream>>>(stats, gm[0], bm[0], 64, ss);
    // Layer 1 (64 -> 64)
    conv_mfma<64, 64, 64><<<dim3(79, 1, NB), dim3(256), 0, stream>>>(P, ss, Wm[1], Q);
    chan_stats<<<dim3(64, NB), dim3(256), 0, stream>>>(Q, 64, stats + 512);
    bn_finalize<<<dim3(1), dim3(256), 0, stream>>>(stats + 512, gm[1], bm[1], 64, ss + 512);
    // Layer 2 (64 -> 64)
    conv_mfma<64, 64, 64><<<dim3(79, 1, NB), dim3(256), 0, stream>>>(Q, ss + 512, Wm[2], P);
    chan_stats<<<dim3(64, NB), dim3(256), 0, stream>>>(P, 64, stats + 1024);
    bn_finalize<<<dim3(1), dim3(256), 0, stream>>>(stats + 1024, gm[2], bm[2], 64, ss + 1024);
    // Layer 3 (64 -> 128)
    conv_mfma<64, 128, 128><<<dim3(79, 1, NB), dim3(256), 0, stream>>>(P, ss + 1024, Wm[3], Q);
    chan_stats<<<dim3(128, NB), dim3(256), 0, stream>>>(Q, 128, stats + 1536);
    bn_finalize<<<dim3(1), dim3(256), 0, stream>>>(stats + 1536, gm[3], bm[3], 128, ss + 1536);
    // Layer 4 (128 -> 256); writes R (P is dead now)
    conv_mfma<128, 256, 128><<<dim3(79, 2, NB), dim3(256), 0, stream>>>(Q, ss + 1536, Wm[4], R);
    chan_stats<<<dim3(256, NB), dim3(256), 0, stream>>>(R, 256, stats + 2048);
    bn_finalize<<<dim3(1), dim3(256), 0, stream>>>(stats + 2048, gm[4], bm[4], 256, ss + 2048);

    // Covariance path (Q dead; its region hosts covP; NS buffers go to R
    // which dies after fsum/cov_mfma complete)
    fsum_ker<<<dim3(256, NB), dim3(256), 0, stream>>>(R, ss + 2048, fsumb);
    cov_mfma<<<dim3(COV_CHUNKS, 3, NB), dim3(256), 0, stream>>>(R, ss + 2048, covP);
    covfin_ker<<<dim3(256, NB), dim3(256), 0, stream>>>(covP, fsumb, Y0, trace);
    ns_init<<<dim3(4096), dim3(256), 0, stream>>>(Y0, Z0, trace);

    // Newton–Schulz iterations for principal sqrt
    float* Yc = Y0; float* Zc = Z0; float* Yn = Y1; float* Zn = Z1;
    for (int it = 0; it < NS_ITERS; ++it) {
        ns_gemm<<<dim3(16, NB), dim3(256), 0, stream>>>(Zc, Yc, Mb, -1.f, 3.f);
        ns_gemm_pair<<<dim3(16, NB, 2), dim3(256), 0, stream>>>(Yc, Mb, Zc, Yn, Zn);
        float* ty = Yc; Yc = Yn; Yn = ty;
        float* tz = Zc; Zc = Zn; Zn = tz;
    }

    fc_ker<<<dim3(512, 4), dim3(256), 0, stream>>>(Yc, trace, Wfc, outpre);
    norm_ker<<<dim3(NB), dim3(256), 0, stream>>>(outpre, bfc, (float*)d_out);
}

// Round 3
// 1007.399 us; speedup vs baseline: 2.5672x; 2.2647x over previous
//
#include <hip/hip_runtime.h>
#include <cmath>

constexpr int NB   = 16;      // batch
constexpr int NPTS = 10000;   // points per batch
constexpr int NBN  = NB * NPTS;   // 160000
constexpr int NS_ITERS = 18;
constexpr int COV_CHUNKS = 20;    // 500 points each
constexpr int CHUNK_PTS  = 500;
constexpr int COV_KK     = 16;    // 16*32 = 512 >= 500

typedef _Float16 f16x8 __attribute__((ext_vector_type(8)));
typedef float  f32x4  __attribute__((ext_vector_type(4)));
typedef unsigned short ushort4v __attribute__((ext_vector_type(4)));
typedef unsigned short ushort8v __attribute__((ext_vector_type(8)));

// ---------------------------------------------------------------------------
// Layer 0: 3 -> 64, no input BN
// ---------------------------------------------------------------------------
__global__ __launch_bounds__(256) void conv0_ker(const float* __restrict__ pts,
                                                 const float* __restrict__ W,
                                                 float* __restrict__ y) {
    int g = blockIdx.x * 256 + threadIdx.x;          // 0..159999
    int b = g / NPTS;
    int n = g - b * NPTS;
    float p0 = pts[3 * (size_t)g + 0];
    float p1 = pts[3 * (size_t)g + 1];
    float p2 = pts[3 * (size_t)g + 2];
    float* yp = y + ((size_t)b * 64) * NPTS + n;
    for (int o = 0; o < 64; ++o) {
        float v = W[3 * o] * p0 + W[3 * o + 1] * p1 + W[3 * o + 2] * p2;
        yp[(size_t)o * NPTS] = v;
    }
}

// ---------------------------------------------------------------------------
// split-fp16 helpers (hi = fp16(v), lo = fp16(v - hi)): 3-MFMA product keeps
// ~2^-22 relative accuracy, effectively fp32 for this pipeline.
// ---------------------------------------------------------------------------
__device__ __forceinline__ unsigned short f2h(float f) {
    return __builtin_bit_cast(unsigned short, (_Float16)f);
}
__device__ __forceinline__ float hres(float f) {
    return f - (float)(_Float16)f;
}
// LDS XOR-swizzle on ushort index (byte bits 5-6 ^= bits 8-9), 8-us aligned
__device__ __forceinline__ int swzu(int us) {
    return us ^ (((us >> 7) & 3) << 4);
}

// ---------------------------------------------------------------------------
// MFMA conv layer: y[b, ob+o, n] = sum_c W[ob+o, c] * relu(bn(x[b, c, n]))
// Block tile: OTILE x 128 points; waves 2x2 (OTILE=128) or 1x4 (OTILE=64).
// ---------------------------------------------------------------------------
template <int CIN, int COUT, int OTILE>
__global__ __launch_bounds__(256) void conv_mfma(const float* __restrict__ xin,
                                                 const float* __restrict__ ss,
                                                 const float* __restrict__ W,
                                                 float* __restrict__ y) {
    constexpr int OT = OTILE / 16;
    constexpr int WM = 4;
    constexpr int WN = (OTILE == 128) ? 4 : 2;
    __shared__ unsigned short Xp[2][8 * 512];
    __shared__ unsigned short Wp[2][OT * 512];

    const int tid  = threadIdx.x;
    const int lane = tid & 63;
    const int w    = tid >> 6;
    const int wr   = (OTILE == 128) ? (w & 1) : 0;
    const int wc   = (OTILE == 128) ? (w >> 1) : w;

    const int nb = blockIdx.x * 128;
    const int ob = blockIdx.y * OTILE;
    const int b  = blockIdx.z;

    f32x4 acc[WM][WN];
#pragma unroll
    for (int m = 0; m < WM; ++m)
#pragma unroll
        for (int n = 0; n < WN; ++n) acc[m][n] = (f32x4){0.f, 0.f, 0.f, 0.f};

    const int xn = tid & 127;
    const int th = tid >> 7;
    const bool nok = (nb + xn) < NPTS;

#pragma unroll 1
    for (int kc = 0; kc < CIN; kc += 32) {
        __syncthreads();
        // ---- stage W[ob..ob+OTILE)[kc..kc+32) as split-fp16 A panels ----
#pragma unroll
        for (int i = 0; i < OTILE / 32; ++i) {
            int l = i * 256 + tid;
            int o = l >> 3, k4 = (l & 7) << 2;
            float4 v = *(const float4*)(W + (size_t)(ob + o) * CIN + kc + k4);
            ushort4v h4, l4;
            h4[0] = f2h(v.x); l4[0] = f2h(hres(v.x));
            h4[1] = f2h(v.y); l4[1] = f2h(hres(v.y));
            h4[2] = f2h(v.z); l4[2] = f2h(hres(v.z));
            h4[3] = f2h(v.w); l4[3] = f2h(hres(v.w));
            int us = swzu((o >> 4) * 512 + ((k4 >> 3) * 16 + (o & 15)) * 8 + (k4 & 7));
            *(ushort4v*)&Wp[0][us] = h4;
            *(ushort4v*)&Wp[1][us] = l4;
        }
        // ---- stage relu(bn(x))[kc..kc+32)[nb..nb+128) as split-fp16 B panels ----
#pragma unroll
        for (int qq = 0; qq < 2; ++qq) {
            int q = th * 2 + qq;
            const float* xb = xin + ((size_t)(b * CIN + kc + q * 8)) * NPTS + nb + xn;
            float f[8];
#pragma unroll
            for (int j = 0; j < 8; ++j) {
                float v = nok ? xb[(size_t)j * NPTS] : 0.f;
                int c = kc + q * 8 + j;
                f[j] = fmaxf(fmaf(v, ss[c], ss[256 + c]), 0.f);
            }
            ushort8v h8, l8;
#pragma unroll
            for (int j = 0; j < 8; ++j) {
                h8[j] = f2h(f[j]);
                l8[j] = f2h(hres(f[j]));
            }
            int us = swzu((xn >> 4) * 512 + (q * 16 + (xn & 15)) * 8);
            *(ushort8v*)&Xp[0][us] = h8;
            *(ushort8v*)&Xp[1][us] = l8;
        }
        __syncthreads();

        f16x8 ah[WM], al[WM], bh[WN], bl[WN];
#pragma unroll
        for (int m = 0; m < WM; ++m) {
            int us = swzu((wr * WM + m) * 512 + lane * 8);
            ah[m] = *(const f16x8*)&Wp[0][us];
            al[m] = *(const f16x8*)&Wp[1][us];
        }
#pragma unroll
        for (int n = 0; n < WN; ++n) {
            int us = swzu((wc * WN + n) * 512 + lane * 8);
            bh[n] = *(const f16x8*)&Xp[0][us];
            bl[n] = *(const f16x8*)&Xp[1][us];
        }
#pragma unroll
        for (int m = 0; m < WM; ++m)
#pragma unroll
            for (int n = 0; n < WN; ++n) {
                acc[m][n] = __builtin_amdgcn_mfma_f32_16x16x32_f16(ah[m], bh[n], acc[m][n], 0, 0, 0);
                acc[m][n] = __builtin_amdgcn_mfma_f32_16x16x32_f16(ah[m], bl[n], acc[m][n], 0, 0, 0);
                acc[m][n] = __builtin_amdgcn_mfma_f32_16x16x32_f16(al[m], bh[n], acc[m][n], 0, 0, 0);
            }
    }

    // ---- epilogue ----
    const int ro = (lane >> 4) * 4;
    const int co = lane & 15;
#pragma unroll
    for (int m = 0; m < WM; ++m) {
        int o = ob + wr * (WM * 16) + m * 16 + ro;
#pragma unroll
        for (int n = 0; n < WN; ++n) {
            int col = nb + wc * (WN * 16) + n * 16 + co;
            if (col < NPTS) {
                float* yp = y + ((size_t)(b * COUT + o)) * NPTS + col;
#pragma unroll
                for (int r = 0; r < 4; ++r)
                    yp[(size_t)r * NPTS] = acc[m][n][r];
            }
        }
    }
}

// ---------------------------------------------------------------------------
// Per-channel sum / sumsq over (batch, points)  -> stats[c], stats[C+c]
// ---------------------------------------------------------------------------
__global__ void chan_stats(const float* __restrict__ y, int C, float* __restrict__ stats) {
    int c = blockIdx.x, b = blockIdx.y, t = threadIdx.x;
    const float* p = y + ((size_t)(b * C + c)) * NPTS;
    float s = 0.f, q = 0.f;
    for (int n = t; n < NPTS; n += 256) {
        float v = p[n];
        s += v;
        q = fmaf(v, v, q);
    }
    for (int off = 32; off; off >>= 1) {
        s += __shfl_down(s, off);
        q += __shfl_down(q, off);
    }
    __shared__ float ls[4], lq[4];
    if ((t & 63) == 0) { ls[t >> 6] = s; lq[t >> 6] = q; }
    __syncthreads();
    if (t == 0) {
        atomicAdd(&stats[c],     ls[0] + ls[1] + ls[2] + ls[3]);
        atomicAdd(&stats[C + c], lq[0] + lq[1] + lq[2] + lq[3]);
    }
}

__global__ void bn_finalize(const float* __restrict__ stats, const float* __restrict__ g,
                            const float* __restrict__ bi, int C, float* __restrict__ ss) {
    int c = threadIdx.x;
    if (c < C) {
        float mu  = stats[c] * (1.f / NBN);
        float var = stats[C + c] * (1.f / NBN) - mu * mu;
        float r = rsqrtf(var + 1e-5f);
        float s = g[c] * r;
        ss[c] = s;
        ss[256 + c] = bi[c] - mu * s;
    }
}

// ---------------------------------------------------------------------------
// Split-fp16 MFMA second moment: covP[chunk][b][tile] 128x128 += F F^T
// over CHUNK_PTS points.  Also accumulates per-(b,channel) relu-sums into
// fsumb (tiles 0/1 cover every channel exactly once per chunk).
// grid: (COV_CHUNKS, 3 tiles{(0,0),(1,1),(0,1)}, 16 batches) = 960 blocks.
// ---------------------------------------------------------------------------
__device__ __forceinline__ int swz8(int byteoff) {
    return byteoff ^ (((byteoff >> 8) & 3) << 5);
}

__global__ __launch_bounds__(256) void cov_mfma(const float* __restrict__ y4,
                                                const float* __restrict__ ss,
                                                float* __restrict__ covP,
                                                float* __restrict__ fsumb) {
    __shared__ unsigned short pan[2][2][4096];   // [panel][hi/lo][8 frag-tiles * 512]

    const int chunk = blockIdx.x;
    const int tile  = blockIdx.y;
    const int b     = blockIdx.z;
    const int ti = (tile == 1) ? 1 : 0;
    const int tj = (tile == 0) ? 0 : 1;
    const int npan = (tile == 2) ? 2 : 1;

    const int tid  = threadIdx.x;
    const int lane = tid & 63;
    const int w    = tid >> 6;
    const int wr   = w & 1, wc = w >> 1;

    const int n0c = chunk * CHUNK_PTS;

    f32x4 acc[4][4];
#pragma unroll
    for (int m = 0; m < 4; ++m)
#pragma unroll
        for (int n = 0; n < 4; ++n) acc[m][n] = (f32x4){0.f, 0.f, 0.f, 0.f};

    // staging assignment: 8 point-groups (4 pts) x 32 channel-bases
    const int g   = tid & 7;
    const int chb = tid >> 3;          // 0..31
    const int p4  = g * 4;             // point offset in 32-chunk
    const int q   = p4 >> 3, j0 = p4 & 7;

    float fs[4] = {0.f, 0.f, 0.f, 0.f};   // per-thread channel relu-sums (tiles 0/1)

#pragma unroll 1
    for (int kk = 0; kk < COV_KK; ++kk) {        // 16*32 = 512 >= 500
        const int nbase = n0c + kk * 32;
        __syncthreads();
        for (int p = 0; p < npan; ++p) {
            const int pcb = (p ? tj : ti) * 128;
#pragma unroll
            for (int i = 0; i < 4; ++i) {
                const int ch = chb + 32 * i;
                float4 v = make_float4(0.f, 0.f, 0.f, 0.f);
                if (kk * 32 + p4 < CHUNK_PTS) {
                    v = *(const float4*)(y4 + ((size_t)(b * 256 + pcb + ch)) * NPTS + nbase + p4);
                    float sc = ss[pcb + ch], sh = ss[256 + pcb + ch];
                    v.x = fmaxf(fmaf(v.x, sc, sh), 0.f);
                    v.y = fmaxf(fmaf(v.y, sc, sh), 0.f);
                    v.z = fmaxf(fmaf(v.z, sc, sh), 0.f);
                    v.w = fmaxf(fmaf(v.w, sc, sh), 0.f);
                }
                if (npan == 1) fs[i] += (v.x + v.y) + (v.z + v.w);
                ushort4v h4, l4;
                h4[0] = f2h(v.x); l4[0] = f2h(hres(v.x));
                h4[1] = f2h(v.y); l4[1] = f2h(hres(v.y));
                h4[2] = f2h(v.z); l4[2] = f2h(hres(v.z));
                h4[3] = f2h(v.w); l4[3] = f2h(hres(v.w));
                const int addr = (ch >> 4) * 512 + (q * 16 + (ch & 15)) * 8 + j0;
                const int sa = swz8(addr * 2) >> 1;
                *(ushort4v*)&pan[p][0][sa] = h4;
                *(ushort4v*)&pan[p][1][sa] = l4;
            }
        }
        __syncthreads();

        const unsigned short* Ah = pan[0][0];
        const unsigned short* Al = pan[0][1];
        const unsigned short* Bh = pan[npan - 1][0];
        const unsigned short* Bl = pan[npan - 1][1];

        f16x8 ah[4], al[4], bh[4], bl[4];
#pragma unroll
        for (int m = 0; m < 4; ++m) {
            int t8 = (wr * 4 + m) * 512 + lane * 8;
            int sa = swz8(t8 * 2) >> 1;
            ah[m] = *(const f16x8*)&Ah[sa];
            al[m] = *(const f16x8*)&Al[sa];
        }
#pragma unroll
        for (int n = 0; n < 4; ++n) {
            int t8 = (wc * 4 + n) * 512 + lane * 8;
            int sa = swz8(t8 * 2) >> 1;
            bh[n] = *(const f16x8*)&Bh[sa];
            bl[n] = *(const f16x8*)&Bl[sa];
        }
#pragma unroll
        for (int m = 0; m < 4; ++m)
#pragma unroll
            for (int n = 0; n < 4; ++n) {
                acc[m][n] = __builtin_amdgcn_mfma_f32_16x16x32_f16(ah[m], bh[n], acc[m][n], 0, 0, 0);
                acc[m][n] = __builtin_amdgcn_mfma_f32_16x16x32_f16(ah[m], bl[n], acc[m][n], 0, 0, 0);
                acc[m][n] = __builtin_amdgcn_mfma_f32_16x16x32_f16(al[m], bh[n], acc[m][n], 0, 0, 0);
            }
    }

    // fused per-channel relu-sum contribution (tiles 0/1 only)
    if (npan == 1) {
#pragma unroll
        for (int i = 0; i < 4; ++i) {
            float s = fs[i];
            s += __shfl_xor(s, 1);
            s += __shfl_xor(s, 2);
            s += __shfl_xor(s, 4);
            if (g == 0)
                atomicAdd(&fsumb[b * 256 + ti * 128 + chb + 32 * i], s);
        }
    }

    // epilogue: packed per-(chunk,b,tile) 128x128 partial buffer (no atomics)
    float* outp = covP + (((size_t)(chunk * NB + b) * 3 + tile) << 14);
    const int rowb = wr * 64;
    const int colb = wc * 64;
#pragma unroll
    for (int m = 0; m < 4; ++m)
#pragma unroll
        for (int n = 0; n < 4; ++n)
#pragma unroll
            for (int r = 0; r < 4; ++r) {
                int row = rowb + m * 16 + (lane >> 4) * 4 + r;
                int col = colb + n * 16 + (lane & 15);
                outp[(row << 7) + col] = acc[m][n][r];
            }
}

// ---------------------------------------------------------------------------
// cov = (sum_q covP[q])/N - m fbar^T - fbar m^T + m m^T ; mirror tile (1,0)
// covP layout: [chunk][b][tile 0:(0,0) 1:(1,1) 2:(0,1)][128][128]
// ---------------------------------------------------------------------------
__global__ void covfin_ker(const float* __restrict__ covP, const float* __restrict__ fsumb,
                           float* __restrict__ Y0, float* __restrict__ trace) {
    int r = blockIdx.x, b = blockIdx.y, c = threadIdx.x;
    float fbr = fsumb[b * 256 + r] * (1.f / NPTS);
    float fbc = fsumb[b * 256 + c] * (1.f / NPTS);
    float mr = 0.f, mc = 0.f;
    for (int q = 0; q < NB; ++q) {
        mr += fsumb[q * 256 + r];
        mc += fsumb[q * 256 + c];
    }
    mr *= (1.f / NBN);
    mc *= (1.f / NBN);
    int tile, rr, cc;
    if (r < 128 && c < 128)        { tile = 0; rr = r;       cc = c; }
    else if (r >= 128 && c >= 128) { tile = 1; rr = r - 128; cc = c - 128; }
    else if (r < 128)              { tile = 2; rr = r;       cc = c - 128; }   // (0,1)
    else                           { tile = 2; rr = c;       cc = r - 128; }   // (1,0) mirror
    size_t base = (((size_t)b * 3 + tile) << 14) + ((size_t)rr << 7) + cc;
    float m5 = 0.f;
#pragma unroll
    for (int q = 0; q < COV_CHUNKS; ++q)
        m5 += covP[(size_t)q * (NB * 3 * 16384) + base];
    float v = m5 * (1.f / NPTS) - fbr * mc - mr * fbc + mr * mc;
    Y0[((size_t)b << 16) + ((size_t)r << 8) + c] = v;
    if (c == r) atomicAdd(&trace[b], v);
}

__global__ void ns_init(float* __restrict__ Y0, float* __restrict__ Z0,
                        const float* __restrict__ trace) {
    int i = blockIdx.x * 256 + threadIdx.x;   // 16*65536 total
    int b = i >> 16, rc = i & 65535;
    float inv = 1.f / trace[b];
    Y0[i] *= inv;
    Z0[i] = ((rc >> 8) == (rc & 255)) ? 1.f : 0.f;
}

// ---------------------------------------------------------------------------
// Newton-Schulz batched 256x256 GEMM via split-fp16 MFMA.
// O = diag*I + scale*(A.B); block computes 64x64 tile, K=256 in 8 steps.
// Staging layout (per panel, 64 f x 32 k): (f>>4)*512 + (kq*16+(f&15))*8 + j.
// kq == wave id -> staging writes are bank-conflict-free; frag reads linear.
// ---------------------------------------------------------------------------
__device__ __forceinline__ void ns_body(const float* __restrict__ Ab,
                                        const float* __restrict__ Bb,
                                        float* __restrict__ Ob,
                                        float scale, float diag, int tile, int tid,
                                        unsigned short* Ap0, unsigned short* Ap1,
                                        unsigned short* Bp0, unsigned short* Bp1) {
    const int lane = tid & 63;
    const int w    = tid >> 6;
    const int wr   = w & 1, wc = w >> 1;
    const int tr = (tile >> 2) * 64, tc = (tile & 3) * 64;

    f32x4 acc[2][2];
#pragma unroll
    for (int m = 0; m < 2; ++m)
#pragma unroll
        for (int n = 0; n < 2; ++n) acc[m][n] = (f32x4){0.f, 0.f, 0.f, 0.f};

    const int fA = tid & 63;       // staged row (A) / col (B)
    const int kq = tid >> 6;       // k-subblock (== wave id)

#pragma unroll 1
    for (int kc = 0; kc < 256; kc += 32) {
        __syncthreads();
        const float* ap = Ab + (size_t)(tr + fA) * 256 + kc + kq * 8;
        float av[8];
        *(float4*)&av[0] = *(const float4*)ap;
        *(float4*)&av[4] = *(const float4*)(ap + 4);
        const float* bp = Bb + (size_t)(kc + kq * 8) * 256 + tc + fA;
        float bv[8];
#pragma unroll
        for (int j = 0; j < 8; ++j) bv[j] = bp[(size_t)j * 256];
        ushort8v ah8, al8, bh8, bl8;
#pragma unroll
        for (int j = 0; j < 8; ++j) {
            ah8[j] = f2h(av[j]); al8[j] = f2h(hres(av[j]));
            bh8[j] = f2h(bv[j]); bl8[j] = f2h(hres(bv[j]));
        }
        const int ua = (fA >> 4) * 512 + (kq * 16 + (fA & 15)) * 8;
        *(ushort8v*)&Ap0[ua] = ah8;
        *(ushort8v*)&Ap1[ua] = al8;
        *(ushort8v*)&Bp0[ua] = bh8;
        *(ushort8v*)&Bp1[ua] = bl8;
        __syncthreads();

        f16x8 a_h[2], a_l[2], b_h[2], b_l[2];
#pragma unroll
        for (int m = 0; m < 2; ++m) {
            int u = (wr * 2 + m) * 512 + lane * 8;
            a_h[m] = *(const f16x8*)&Ap0[u];
            a_l[m] = *(const f16x8*)&Ap1[u];
        }
#pragma unroll
        for (int n = 0; n < 2; ++n) {
            int u = (wc * 2 + n) * 512 + lane * 8;
            b_h[n] = *(const f16x8*)&Bp0[u];
            b_l[n] = *(const f16x8*)&Bp1[u];
        }
#pragma unroll
        for (int m = 0; m < 2; ++m)
#pragma unroll
            for (int n = 0; n < 2; ++n) {
                acc[m][n] = __builtin_amdgcn_mfma_f32_16x16x32_f16(a_h[m], b_h[n], acc[m][n], 0, 0, 0);
                acc[m][n] = __builtin_amdgcn_mfma_f32_16x16x32_f16(a_h[m], b_l[n], acc[m][n], 0, 0, 0);
                acc[m][n] = __builtin_amdgcn_mfma_f32_16x16x32_f16(a_l[m], b_h[n], acc[m][n], 0, 0, 0);
            }
    }

    const int ro = (lane >> 4) * 4, co = lane & 15;
#pragma unroll
    for (int m = 0; m < 2; ++m)
#pragma unroll
        for (int n = 0; n < 2; ++n) {
            int row = tr + wr * 32 + m * 16 + ro;
            int col = tc + wc * 32 + n * 16 + co;
#pragma unroll
            for (int r = 0; r < 4; ++r) {
                float v = scale * acc[m][n][r] + (((row + r) == col) ? diag : 0.f);
                Ob[(size_t)(row + r) * 256 + col] = v;
            }
        }
}

__global__ __launch_bounds__(256) void ns_gemm(const float* __restrict__ A,
                                               const float* __restrict__ B,
                                               float* __restrict__ O,
                                               float scale, float diag) {
    __shared__ unsigned short Ap[2][2048], Bp[2][2048];
    size_t off = (size_t)blockIdx.y << 16;
    ns_body(A + off, B + off, O + off, scale, diag, blockIdx.x, threadIdx.x,
            Ap[0], Ap[1], Bp[0], Bp[1]);
}

__global__ __launch_bounds__(256) void ns_gemm_pair(const float* __restrict__ Y,
                                                    const float* __restrict__ Mm,
                                                    const float* __restrict__ Z,
                                                    float* __restrict__ Yn,
                                                    float* __restrict__ Zn) {
    __shared__ unsigned short Ap[2][2048], Bp[2][2048];
    size_t off = (size_t)blockIdx.y << 16;
    if (blockIdx.z == 0)
        ns_body(Y + off, Mm + off, Yn + off, 0.5f, 0.f, blockIdx.x, threadIdx.x,
                Ap[0], Ap[1], Bp[0], Bp[1]);
    else
        ns_body(Mm + off, Z + off, Zn + off, 0.5f, 0.f, blockIdx.x, threadIdx.x,
                Ap[0], Ap[1], Bp[0], Bp[1]);
}

// ---------------------------------------------------------------------------
// FC: outpre[b,o] += sum_k sqrt(trace[b])*Yf[b,k] * Wfc[o,k]
// ---------------------------------------------------------------------------
__global__ __launch_bounds__(256) void fc_ker(const float* __restrict__ Yf,
                                              const float* __restrict__ trace,
                                              const float* __restrict__ Wfc,
                                              float* __restrict__ outpre) {
    int kc = blockIdx.x;
    int ot = blockIdx.y;
    int t = threadIdx.x;
    __shared__ float Wl[64][129];
    __shared__ float Vl[16][129];
#pragma unroll
    for (int i = 0; i < 32; ++i) {
        int l = i * 256 + t;
        int o = l >> 7, k = l & 127;
        Wl[o][k] = Wfc[(size_t)(ot * 64 + o) * 65536 + kc * 128 + k];
    }
#pragma unroll
    for (int i = 0; i < 8; ++i) {
        int l = i * 256 + t;
        int bb = l >> 7, k = l & 127;
        Vl[bb][k] = sqrtf(trace[bb]) * Yf[((size_t)bb << 16) + kc * 128 + k];
    }
    __syncthreads();
    int ol = t & 63, bg = t >> 6;
    float a0 = 0.f, a1 = 0.f, a2 = 0.f, a3 = 0.f;
    for (int k = 0; k < 128; ++k) {
        float w = Wl[ol][k];
        a0 = fmaf(w, Vl[bg * 4 + 0][k], a0);
        a1 = fmaf(w, Vl[bg * 4 + 1][k], a1);
        a2 = fmaf(w, Vl[bg * 4 + 2][k], a2);
        a3 = fmaf(w, Vl[bg * 4 + 3][k], a3);
    }
    int o = ot * 64 + ol;
    atomicAdd(&outpre[(bg * 4 + 0) * 256 + o], a0);
    atomicAdd(&outpre[(bg * 4 + 1) * 256 + o], a1);
    atomicAdd(&outpre[(bg * 4 + 2) * 256 + o], a2);
    atomicAdd(&outpre[(bg * 4 + 3) * 256 + o], a3);
}

__global__ void norm_ker(const float* __restrict__ outpre, const float* __restrict__ bfc,
                         float* __restrict__ dout) {
    int b = blockIdx.x, t = threadIdx.x;
    float v = outpre[b * 256 + t] + bfc[t];
    float q = v * v;
    for (int off = 32; off; off >>= 1) q += __shfl_xor(q, off);
    __shared__ float lq[4];
    __shared__ float snorm;
    if ((t & 63) == 0) lq[t >> 6] = q;
    __syncthreads();
    if (t == 0) snorm = fmaxf(sqrtf(lq[0] + lq[1] + lq[2] + lq[3]), 1e-12f);
    __syncthreads();
    dout[b * 256 + t] = v / snorm;
}

// ---------------------------------------------------------------------------
extern "C" void kernel_launch(void* const* d_in, const int* in_sizes, int n_in,
                              void* d_out, int out_size, void* d_ws, size_t ws_size,
                              hipStream_t stream) {
    (void)in_sizes; (void)n_in; (void)out_size; (void)ws_size;
    const float* pts = (const float*)d_in[0];
    const float* Wm[5]; const float* gm[5]; const float* bm[5];
    for (int i = 0; i < 5; ++i) {
        Wm[i] = (const float*)d_in[1 + 3 * i];
        gm[i] = (const float*)d_in[2 + 3 * i];
        bm[i] = (const float*)d_in[3 + 3 * i];
    }
    const float* Wfc = (const float*)d_in[16];
    const float* bfc = (const float*)d_in[17];

    float* ws     = (float*)d_ws;
    float* stats  = ws;                  // 2560
    float* fsumb  = ws + 2560;           // 4096
    float* trace  = ws + 6656;           // 16
    float* outpre = ws + 6672;           // 4096
    float* ss     = ws + 10768;          // 2560
    float* R      = ws + 16384;          // 256ch fp32: 40,960,000 floats (y4)
    float* P      = R;                   // 64ch view (L0/L2 out)
    float* Q      = R + (size_t)NB * 256 * NPTS;   // 128ch: 20,480,000 floats
    // cov partials alias the (then-dead) Q region:
    // 20 chunks * 16 b * 3 tiles * 16384 = 15,728,640 floats < 20.48M
    float* covP   = Q;
    // NS buffers alias the (then-dead) R region (R dead after cov_mfma):
    float* Y0     = R;
    float* Y1     = Y0 + 1048576;
    float* Z0     = Y1 + 1048576;
    float* Z1     = Z0 + 1048576;
    float* Mb     = Z1 + 1048576;        // 5.24M floats << 40.96M of R

    hipMemsetAsync(ws, 0, 16384 * sizeof(float), stream);

    // Layer 0 (3 -> 64)
    conv0_ker<<<dim3(NBN / 256), dim3(256), 0, stream>>>(pts, Wm[0], P);
    chan_stats<<<dim3(64, NB), dim3(256), 0, stream>>>(P, 64, stats);
    bn_finalize<<<dim3(1), dim3(256), 0, stream>>>(stats, gm[0], bm[0], 64, ss);
    // Layer 1 (64 -> 64)
    conv_mfma<64, 64, 64><<<dim3(79, 1, NB), dim3(256), 0, stream>>>(P, ss, Wm[1], Q);
    chan_stats<<<dim3(64, NB), dim3(256), 0, stream>>>(Q, 64, stats + 512);
    bn_finalize<<<dim3(1), dim3(256), 0, stream>>>(stats + 512, gm[1], bm[1], 64, ss + 512);
    // Layer 2 (64 -> 64)
    conv_mfma<64, 64, 64><<<dim3(79, 1, NB), dim3(256), 0, stream>>>(Q, ss + 512, Wm[2], P);
    chan_stats<<<dim3(64, NB), dim3(256), 0, stream>>>(P, 64, stats + 1024);
    bn_finalize<<<dim3(1), dim3(256), 0, stream>>>(stats + 1024, gm[2], bm[2], 64, ss + 1024);
    // Layer 3 (64 -> 128)
    conv_mfma<64, 128, 128><<<dim3(79, 1, NB), dim3(256), 0, stream>>>(P, ss + 1024, Wm[3], Q);
    chan_stats<<<dim3(128, NB), dim3(256), 0, stream>>>(Q, 128, stats + 1536);
    bn_finalize<<<dim3(1), dim3(256), 0, stream>>>(stats + 1536, gm[3], bm[3], 128, ss + 1536);
    // Layer 4 (128 -> 256); writes R (P is dead now)
    conv_mfma<128, 256, 128><<<dim3(79, 2, NB), dim3(256), 0, stream>>>(Q, ss + 1536, Wm[4], R);
    chan_stats<<<dim3(256, NB), dim3(256), 0, stream>>>(R, 256, stats + 2048);
    bn_finalize<<<dim3(1), dim3(256), 0, stream>>>(stats + 2048, gm[4], bm[4], 256, ss + 2048);

    // Covariance path (fsum fused into cov_mfma; Q region hosts covP;
    // NS buffers go to R which dies after cov_mfma completes)
    cov_mfma<<<dim3(COV_CHUNKS, 3, NB), dim3(256), 0, stream>>>(R, ss + 2048, covP, fsumb);
    covfin_ker<<<dim3(256, NB), dim3(256), 0, stream>>>(covP, fsumb, Y0, trace);
    ns_init<<<dim3(4096), dim3(256), 0, stream>>>(Y0, Z0, trace);

    // Newton–Schulz iterations for principal sqrt (split-fp16 MFMA)
    float* Yc = Y0; float* Zc = Z0; float* Yn = Y1; float* Zn = Z1;
    for (int it = 0; it < NS_ITERS; ++it) {
        ns_gemm<<<dim3(16, NB), dim3(256), 0, stream>>>(Zc, Yc, Mb, -1.f, 3.f);
        ns_gemm_pair<<<dim3(16, NB, 2), dim3(256), 0, stream>>>(Yc, Mb, Zc, Yn, Zn);
        float* ty = Yc; Yc = Yn; Yn = ty;
        float* tz = Zc; Zc = Zn; Zn = tz;
    }

    fc_ker<<<dim3(512, 4), dim3(256), 0, stream>>>(Yc, trace, Wfc, outpre);
    norm_ker<<<dim3(NB), dim3(256), 0, stream>>>(outpre, bfc, (float*)d_out);
}